// Round 10
// baseline (279.799 us; speedup 1.0000x reference)
//
#include <hip/hip_runtime.h>
#include <hip/hip_bf16.h>
#include <math.h>

#define N_NODES 50000
#define N_EDGES 640000
#define DIM     128
#define NGRAPH  64
#define DOUT    32
#define CAP     64                      // bucket capacity; mean in-deg 12.8, 64 = ~14 sigma
#define CNT_BLOCKS 2500                 // N_EDGES/256
#define LDSS 136                        // 128 + 8 pad (u16)

typedef unsigned short u16;
typedef __attribute__((ext_vector_type(8))) short bf16x8;
typedef __attribute__((ext_vector_type(4))) float f32x4;

__device__ __forceinline__ u16 f2bf(float f) {
    unsigned u = __float_as_uint(f);
    return (u16)((u + 0x7FFFu + ((u >> 16) & 1u)) >> 16);
}
__device__ __forceinline__ float bf2f(u16 h) {
    return __uint_as_float(((unsigned)h) << 16);
}
__device__ __forceinline__ short2 cvt2(float x, float y) {
    __hip_bfloat162 h = __float22bfloat162_rn(make_float2(x, y));
    return *(short2*)&h;
}
__device__ __forceinline__ void upk(unsigned u, float& lo, float& hi) {
    lo = __uint_as_float(u << 16);
    hi = __uint_as_float(u & 0xFFFF0000u);
}

// ======== single-pass bucket adjacency build + W1/W2 swizzle (fused) ========
// bucket[d*CAP + atomicAdd(cnt[d],1)] = s  -- replaces count/scan/finalize/fill chain.
// B frag (16x16x32): lane holds B[k][n], n=lane&15, k=(lane>>4)*8+j  [verified R5-R9]
__global__ __launch_bounds__(256) void k_fill_cvt(const int* __restrict__ src,
                                                  const int* __restrict__ dst,
                                                  int* __restrict__ cnt,
                                                  int* __restrict__ bucket,
                                                  const float* __restrict__ W1,
                                                  const float* __restrict__ W2,
                                                  u16* __restrict__ W1s,
                                                  u16* __restrict__ W2s) {
    int b = blockIdx.x;
    if (b < CNT_BLOCKS) {
        int e = b * 256 + threadIdx.x;
        int d = dst[e];
        int pos = atomicAdd(&cnt[d], 1);
        bucket[d * CAP + pos] = src[e];
    } else {
        int t = (b - CNT_BLOCKS) * 256 + threadIdx.x;   // 0..32767
        int r = t & 16383;
        int j = r & 7, lane = (r >> 3) & 63, kc = (r >> 9) & 3, nt = r >> 11;
        int k = kc * 32 + (lane >> 4) * 8 + j;
        int n = nt * 16 + (lane & 15);
        if (t < 16384) W1s[r] = f2bf(W1[k * 128 + n]);
        else           W2s[r] = f2bf(W2[k * 128 + n]);
    }
}

// ================= MFMA GEMM1: Y(bf16) = dinv[row] * (Xfp32 @ W1) =================
// dinv computed on the fly from cnt. A frag: A[m=lane&15][k=(lane>>4)*8+j];
// C/D: col=lane&15, row=(lane>>4)*4+reg. [verified R5-R9]
__global__ __launch_bounds__(256) void k_gemm1(const float* __restrict__ X,
                                               const u16* __restrict__ Ws,
                                               const int* __restrict__ cnt,
                                               u16* __restrict__ Y) {
    int wv   = threadIdx.x >> 6;
    int lane = threadIdx.x & 63;
    int row0 = blockIdx.x * 64 + wv * 16;
    int m    = lane & 15;
    int quad = lane >> 4;
    int ar = min(row0 + m, N_NODES - 1);
    const float* Arow = X + (size_t)ar * DIM;
    bf16x8 a[4];
#pragma unroll
    for (int kc = 0; kc < 4; ++kc) {
        const float4* p4 = (const float4*)(Arow + kc * 32 + quad * 8);
        float4 p = p4[0], q = p4[1];
        short2 s0 = cvt2(p.x, p.y), s1 = cvt2(p.z, p.w);
        short2 s2 = cvt2(q.x, q.y), s3 = cvt2(q.z, q.w);
        bf16x8 av;
        av[0] = s0.x; av[1] = s0.y; av[2] = s1.x; av[3] = s1.y;
        av[4] = s2.x; av[5] = s2.y; av[6] = s3.x; av[7] = s3.y;
        a[kc] = av;
    }
    float di[4];
#pragma unroll
    for (int r = 0; r < 4; ++r) {
        int rr = row0 + quad * 4 + r;
        di[r] = (rr < N_NODES) ? rsqrtf((float)(cnt[rr] + 1)) : 0.f;
    }
#pragma unroll
    for (int nt = 0; nt < 8; ++nt) {
        f32x4 acc = {0.f, 0.f, 0.f, 0.f};
#pragma unroll
        for (int kc = 0; kc < 4; ++kc) {
            bf16x8 b = *(const bf16x8*)(Ws + ((size_t)(nt * 4 + kc) * 64 + lane) * 8);
            acc = __builtin_amdgcn_mfma_f32_16x16x32_bf16(a[kc], b, acc, 0, 0, 0);
        }
        int col = nt * 16 + m;
#pragma unroll
        for (int r = 0; r < 4; ++r) {
            int rr = row0 + quad * 4 + r;
            if (rr < N_NODES) Y[(size_t)rr * DIM + col] = f2bf(acc[r] * di[r]);
        }
    }
}

// ================= fused agg1 + gemm2 (16 nodes/block; 50000 = 3125*16) =================
__global__ __launch_bounds__(256) void k_agg_gemm(const u16* __restrict__ H,
                                                  const int* __restrict__ bucket,
                                                  const int* __restrict__ cnt,
                                                  const float* __restrict__ bias,
                                                  const u16* __restrict__ Ws,
                                                  u16* __restrict__ Y) {
    __shared__ u16 As[16][LDSS];
    int tid    = threadIdx.x;
    int nloc   = tid >> 4;
    int lane16 = tid & 15;
    int node   = blockIdx.x * 16 + nloc;

    // ---- phase A: quarter-wave aggregate ----
    int deg = cnt[node];
    int e0 = node * CAP, e1 = e0 + deg;
    const uint4* H4 = (const uint4*)H;
    uint4 sv = H4[(size_t)node * 16 + lane16];
    float a0[8], a1[8] = {}, a2[8] = {}, a3[8] = {};
    upk(sv.x, a0[0], a0[1]); upk(sv.y, a0[2], a0[3]);
    upk(sv.z, a0[4], a0[5]); upk(sv.w, a0[6], a0[7]);
    for (int e = e0; e < e1; e += 8) {
        int   idx[8];
        float w[8];
        uint4 v[8];
#pragma unroll
        for (int u = 0; u < 8; ++u) {
            int eu = e + u;
            int ec = min(eu, e1 - 1);
            idx[u] = bucket[ec];
            w[u]   = (eu < e1) ? 1.f : 0.f;
        }
#pragma unroll
        for (int u = 0; u < 8; ++u) v[u] = H4[(size_t)idx[u] * 16 + lane16];
#pragma unroll
        for (int u = 0; u < 8; ++u) {
            float* a = (u & 3) == 0 ? a0 : (u & 3) == 1 ? a1 : (u & 3) == 2 ? a2 : a3;
            float lo, hi;
            upk(v[u].x, lo, hi); a[0] = fmaf(w[u], lo, a[0]); a[1] = fmaf(w[u], hi, a[1]);
            upk(v[u].y, lo, hi); a[2] = fmaf(w[u], lo, a[2]); a[3] = fmaf(w[u], hi, a[3]);
            upk(v[u].z, lo, hi); a[4] = fmaf(w[u], lo, a[4]); a[5] = fmaf(w[u], hi, a[5]);
            upk(v[u].w, lo, hi); a[6] = fmaf(w[u], lo, a[6]); a[7] = fmaf(w[u], hi, a[7]);
        }
    }
    {
        float di = rsqrtf((float)(deg + 1));
        const float4* b4 = (const float4*)bias;
        float4 blo = b4[lane16 * 2], bhi = b4[lane16 * 2 + 1];
        float r0 = fmaxf(di * (a0[0] + a1[0] + a2[0] + a3[0]) + blo.x, 0.f);
        float r1 = fmaxf(di * (a0[1] + a1[1] + a2[1] + a3[1]) + blo.y, 0.f);
        float r2 = fmaxf(di * (a0[2] + a1[2] + a2[2] + a3[2]) + blo.z, 0.f);
        float r3 = fmaxf(di * (a0[3] + a1[3] + a2[3] + a3[3]) + blo.w, 0.f);
        float r4 = fmaxf(di * (a0[4] + a1[4] + a2[4] + a3[4]) + bhi.x, 0.f);
        float r5 = fmaxf(di * (a0[5] + a1[5] + a2[5] + a3[5]) + bhi.y, 0.f);
        float r6 = fmaxf(di * (a0[6] + a1[6] + a2[6] + a3[6]) + bhi.z, 0.f);
        float r7 = fmaxf(di * (a0[7] + a1[7] + a2[7] + a3[7]) + bhi.w, 0.f);
        short2 s0 = cvt2(r0, r1), s1 = cvt2(r2, r3), s2 = cvt2(r4, r5), s3 = cvt2(r6, r7);
        uint4 o;
        o.x = *(unsigned*)&s0; o.y = *(unsigned*)&s1;
        o.z = *(unsigned*)&s2; o.w = *(unsigned*)&s3;
        *(uint4*)(&As[nloc][lane16 * 8]) = o;
    }
    __syncthreads();

    // ---- phase B: 16x128 @ 128x128 MFMA; wave wv owns cols wv*32..wv*32+31 ----
    int wv   = tid >> 6;
    int lane = tid & 63;
    int m    = lane & 15;
    int quad = lane >> 4;
    bf16x8 a[4];
#pragma unroll
    for (int kc = 0; kc < 4; ++kc)
        a[kc] = *(const bf16x8*)(&As[m][kc * 32 + quad * 8]);
    float di[4];
#pragma unroll
    for (int r = 0; r < 4; ++r)
        di[r] = rsqrtf((float)(cnt[blockIdx.x * 16 + quad * 4 + r] + 1));
#pragma unroll
    for (int i = 0; i < 2; ++i) {
        int nt = wv * 2 + i;
        f32x4 acc = {0.f, 0.f, 0.f, 0.f};
#pragma unroll
        for (int kc = 0; kc < 4; ++kc) {
            bf16x8 b = *(const bf16x8*)(Ws + ((size_t)(nt * 4 + kc) * 64 + lane) * 8);
            acc = __builtin_amdgcn_mfma_f32_16x16x32_bf16(a[kc], b, acc, 0, 0, 0);
        }
        int col = nt * 16 + m;
#pragma unroll
        for (int r = 0; r < 4; ++r) {
            int rr = blockIdx.x * 16 + quad * 4 + r;
            Y[(size_t)rr * DIM + col] = f2bf(acc[r] * di[r]);
        }
    }
}

// ================= agg layer 2 (quarter-wave) =================
__global__ __launch_bounds__(256) void k_agg(const u16* __restrict__ H,
                                             const int* __restrict__ bucket,
                                             const int* __restrict__ cnt,
                                             const float* __restrict__ bias,
                                             u16* __restrict__ Out) {
    int node = blockIdx.x * 16 + (threadIdx.x >> 4);
    int lane = threadIdx.x & 15;
    if (node >= N_NODES) return;
    int deg = cnt[node];
    int e0 = node * CAP, e1 = e0 + deg;
    const uint4* H4 = (const uint4*)H;
    uint4 sv = H4[(size_t)node * 16 + lane];
    float a0[8], a1[8] = {}, a2[8] = {}, a3[8] = {};
    upk(sv.x, a0[0], a0[1]); upk(sv.y, a0[2], a0[3]);
    upk(sv.z, a0[4], a0[5]); upk(sv.w, a0[6], a0[7]);
    for (int e = e0; e < e1; e += 8) {
        int   idx[8];
        float w[8];
        uint4 v[8];
#pragma unroll
        for (int u = 0; u < 8; ++u) {
            int eu = e + u;
            int ec = min(eu, e1 - 1);
            idx[u] = bucket[ec];
            w[u]   = (eu < e1) ? 1.f : 0.f;
        }
#pragma unroll
        for (int u = 0; u < 8; ++u) v[u] = H4[(size_t)idx[u] * 16 + lane];
#pragma unroll
        for (int u = 0; u < 8; ++u) {
            float* a = (u & 3) == 0 ? a0 : (u & 3) == 1 ? a1 : (u & 3) == 2 ? a2 : a3;
            float lo, hi;
            upk(v[u].x, lo, hi); a[0] = fmaf(w[u], lo, a[0]); a[1] = fmaf(w[u], hi, a[1]);
            upk(v[u].y, lo, hi); a[2] = fmaf(w[u], lo, a[2]); a[3] = fmaf(w[u], hi, a[3]);
            upk(v[u].z, lo, hi); a[4] = fmaf(w[u], lo, a[4]); a[5] = fmaf(w[u], hi, a[5]);
            upk(v[u].w, lo, hi); a[6] = fmaf(w[u], lo, a[6]); a[7] = fmaf(w[u], hi, a[7]);
        }
    }
    float di = rsqrtf((float)(deg + 1));
    const float4* b4 = (const float4*)bias;
    float4 blo = b4[lane * 2], bhi = b4[lane * 2 + 1];
    float r0 = fmaxf(di * (a0[0] + a1[0] + a2[0] + a3[0]) + blo.x, 0.f);
    float r1 = fmaxf(di * (a0[1] + a1[1] + a2[1] + a3[1]) + blo.y, 0.f);
    float r2 = fmaxf(di * (a0[2] + a1[2] + a2[2] + a3[2]) + blo.z, 0.f);
    float r3 = fmaxf(di * (a0[3] + a1[3] + a2[3] + a3[3]) + blo.w, 0.f);
    float r4 = fmaxf(di * (a0[4] + a1[4] + a2[4] + a3[4]) + bhi.x, 0.f);
    float r5 = fmaxf(di * (a0[5] + a1[5] + a2[5] + a3[5]) + bhi.y, 0.f);
    float r6 = fmaxf(di * (a0[6] + a1[6] + a2[6] + a3[6]) + bhi.z, 0.f);
    float r7 = fmaxf(di * (a0[7] + a1[7] + a2[7] + a3[7]) + bhi.w, 0.f);
    short2 s0 = cvt2(r0, r1), s1 = cvt2(r2, r3), s2 = cvt2(r4, r5), s3 = cvt2(r6, r7);
    uint4 o;
    o.x = *(unsigned*)&s0; o.y = *(unsigned*)&s1;
    o.z = *(unsigned*)&s2; o.w = *(unsigned*)&s3;
    ((uint4*)Out)[(size_t)node * 16 + lane] = o;
}

// ================= fused pool + head: one block per graph =================
// batch is sorted -> binary-search node range; 2-way node-parallel x 4-deep
// unrolled accumulation; 32-lane GEMV + log_softmax. No pooled buffer/atomics.
__global__ __launch_bounds__(256) void k_pool_head(const u16* __restrict__ H,
                                                   const int* __restrict__ batch,
                                                   const float* __restrict__ Wh,
                                                   const float* __restrict__ bh,
                                                   float* __restrict__ out) {
    __shared__ int s_lo, s_hi;
    __shared__ float ps[2][DIM];
    int g = blockIdx.x;
    int t = threadIdx.x;
    if (t == 0) {
        int lo = 0, hi = N_NODES;
        while (lo < hi) { int mid = (lo + hi) >> 1; if (batch[mid] < g) lo = mid + 1; else hi = mid; }
        s_lo = lo;
        lo = 0; hi = N_NODES;
        while (lo < hi) { int mid = (lo + hi) >> 1; if (batch[mid] < g + 1) lo = mid + 1; else hi = mid; }
        s_hi = lo;
    }
    __syncthreads();
    int lo = s_lo, hi = s_hi;
    int half = t >> 7;          // 0/1: interleaved node subsets
    int d    = t & 127;
    float ac0 = 0.f, ac1 = 0.f, ac2 = 0.f, ac3 = 0.f;
    for (int i = lo + half; i < hi; i += 8) {   // 4-deep unroll, stride 2 per half
        int i1 = i + 2, i2 = i + 4, i3 = i + 6;
        u16 h0 = H[(size_t)i * DIM + d];
        u16 h1 = (i1 < hi) ? H[(size_t)i1 * DIM + d] : (u16)0;
        u16 h2 = (i2 < hi) ? H[(size_t)i2 * DIM + d] : (u16)0;
        u16 h3 = (i3 < hi) ? H[(size_t)i3 * DIM + d] : (u16)0;
        ac0 += bf2f(h0); ac1 += bf2f(h1); ac2 += bf2f(h2); ac3 += bf2f(h3);
    }
    ps[half][d] = (ac0 + ac1) + (ac2 + ac3);
    __syncthreads();
    if (t < 32) {
        float lg = bh[t];
#pragma unroll 8
        for (int k = 0; k < DIM; ++k)
            lg = fmaf(ps[0][k] + ps[1][k], Wh[k * DOUT + t], lg);
        float m = lg;
        for (int off = 16; off >= 1; off >>= 1) m = fmaxf(m, __shfl_xor(m, off, 32));
        float ex = expf(lg - m);
        float s = ex;
        for (int off = 16; off >= 1; off >>= 1) s += __shfl_xor(s, off, 32);
        out[g * DOUT + t] = lg - m - logf(s);
    }
}

extern "C" void kernel_launch(void* const* d_in, const int* in_sizes, int n_in,
                              void* d_out, int out_size, void* d_ws, size_t ws_size,
                              hipStream_t stream) {
    const float* x     = (const float*)d_in[0];
    const int*   ei    = (const int*)d_in[1];
    const int*   batch = (const int*)d_in[2];
    const float* W1    = (const float*)d_in[3];
    const float* b1    = (const float*)d_in[4];
    const float* W2    = (const float*)d_in[5];
    const float* b2    = (const float*)d_in[6];
    const float* Wh    = (const float*)d_in[7];
    const float* bh    = (const float*)d_in[8];
    float* out = (float*)d_out;
    const int* src = ei;
    const int* dst = ei + N_EDGES;

    char* ws = (char*)d_ws;
    size_t off = 0;
    auto alloc = [&](size_t bytes) {
        void* p = ws + off;
        off += (bytes + 255) & ~(size_t)255;
        return p;
    };
    u16*   bufA   = (u16*)alloc((size_t)N_NODES * DIM * 2);   // 12.8 MB bf16
    u16*   bufB   = (u16*)alloc((size_t)N_NODES * DIM * 2);   // 12.8 MB bf16
    int*   cnt    = (int*)alloc((size_t)N_NODES * 4);
    int*   bucket = (int*)alloc((size_t)N_NODES * CAP * 4);   // 12.8 MB
    u16*   W1s    = (u16*)alloc((size_t)DIM * DIM * 2);
    u16*   W2s    = (u16*)alloc((size_t)DIM * DIM * 2);
    (void)ws_size; (void)in_sizes; (void)n_in; (void)out_size;

    hipMemsetAsync(cnt, 0, (size_t)N_NODES * 4, stream);

    k_fill_cvt<<<CNT_BLOCKS + 128, 256, 0, stream>>>(src, dst, cnt, bucket, W1, W2, W1s, W2s);

    k_gemm1   <<<(N_NODES + 63) / 64, 256, 0, stream>>>(x, W1s, cnt, bufA);
    k_agg_gemm<<<N_NODES / 16, 256, 0, stream>>>(bufA, bucket, cnt, b1, W2s, bufB);
    k_agg     <<<N_NODES / 16, 256, 0, stream>>>(bufB, bucket, cnt, b2, bufA);

    k_pool_head<<<NGRAPH, 256, 0, stream>>>(bufA, batch, Wh, bh, out);
}

// Round 11
// 209.014 us; speedup vs baseline: 1.3387x; 1.3387x over previous
//
#include <hip/hip_runtime.h>
#include <hip/hip_bf16.h>
#include <math.h>

#define N_NODES 50000
#define N_EDGES 640000
#define DIM     128
#define NGRAPH  64
#define DOUT    32
#define CAP     64                      // bucket capacity; mean in-deg 12.8, 64 = ~14 sigma
#define CNT_BLOCKS 2500                 // N_EDGES/256
#define POOL_CHUNK 32
#define LDSS 136                        // 128 + 8 pad (u16)

typedef unsigned short u16;
typedef __attribute__((ext_vector_type(8))) short bf16x8;
typedef __attribute__((ext_vector_type(4))) float f32x4;

__device__ __forceinline__ u16 f2bf(float f) {
    unsigned u = __float_as_uint(f);
    return (u16)((u + 0x7FFFu + ((u >> 16) & 1u)) >> 16);
}
__device__ __forceinline__ float bf2f(u16 h) {
    return __uint_as_float(((unsigned)h) << 16);
}
__device__ __forceinline__ short2 cvt2(float x, float y) {
    __hip_bfloat162 h = __float22bfloat162_rn(make_float2(x, y));
    return *(short2*)&h;
}
__device__ __forceinline__ void upk(unsigned u, float& lo, float& hi) {
    lo = __uint_as_float(u << 16);
    hi = __uint_as_float(u & 0xFFFF0000u);
}

// ======== single-pass bucket adjacency build + W swizzles + pooled zero (fused) ========
// bucket[d*CAP + atomicAdd(cnt[d],1)] = s  -- one random pass replaces the CSR chain [R10 win].
// B frag (16x16x32): lane holds B[k][n], n=lane&15, k=(lane>>4)*8+j  [verified R5-R10]
__global__ __launch_bounds__(256) void k_fill_cvt(const int* __restrict__ src,
                                                  const int* __restrict__ dst,
                                                  int* __restrict__ cnt,
                                                  int* __restrict__ bucket,
                                                  const float* __restrict__ W1,
                                                  const float* __restrict__ W2,
                                                  u16* __restrict__ W1s,
                                                  u16* __restrict__ W2s,
                                                  float* __restrict__ pooled) {
    int b = blockIdx.x;
    if (b < CNT_BLOCKS) {
        int e = b * 256 + threadIdx.x;
        int d = dst[e];
        int pos = atomicAdd(&cnt[d], 1);
        bucket[d * CAP + pos] = src[e];
    } else if (b < CNT_BLOCKS + 128) {
        int t = (b - CNT_BLOCKS) * 256 + threadIdx.x;   // 0..32767
        int r = t & 16383;
        int j = r & 7, lane = (r >> 3) & 63, kc = (r >> 9) & 3, nt = r >> 11;
        int k = kc * 32 + (lane >> 4) * 8 + j;
        int n = nt * 16 + (lane & 15);
        if (t < 16384) W1s[r] = f2bf(W1[k * 128 + n]);
        else           W2s[r] = f2bf(W2[k * 128 + n]);
    } else {
        int t = (b - CNT_BLOCKS - 128) * 256 + threadIdx.x;
        if (t < NGRAPH * DIM) pooled[t] = 0.f;
    }
}

// ================= MFMA GEMM1: Y(bf16) = dinv[row] * (Xfp32 @ W1) =================
// dinv on the fly from cnt. A frag: A[m=lane&15][k=(lane>>4)*8+j];
// C/D: col=lane&15, row=(lane>>4)*4+reg. [verified R5-R10]
__global__ __launch_bounds__(256) void k_gemm1(const float* __restrict__ X,
                                               const u16* __restrict__ Ws,
                                               const int* __restrict__ cnt,
                                               u16* __restrict__ Y) {
    int wv   = threadIdx.x >> 6;
    int lane = threadIdx.x & 63;
    int row0 = blockIdx.x * 64 + wv * 16;
    int m    = lane & 15;
    int quad = lane >> 4;
    int ar = min(row0 + m, N_NODES - 1);
    const float* Arow = X + (size_t)ar * DIM;
    bf16x8 a[4];
#pragma unroll
    for (int kc = 0; kc < 4; ++kc) {
        const float4* p4 = (const float4*)(Arow + kc * 32 + quad * 8);
        float4 p = p4[0], q = p4[1];
        short2 s0 = cvt2(p.x, p.y), s1 = cvt2(p.z, p.w);
        short2 s2 = cvt2(q.x, q.y), s3 = cvt2(q.z, q.w);
        bf16x8 av;
        av[0] = s0.x; av[1] = s0.y; av[2] = s1.x; av[3] = s1.y;
        av[4] = s2.x; av[5] = s2.y; av[6] = s3.x; av[7] = s3.y;
        a[kc] = av;
    }
    float di[4];
#pragma unroll
    for (int r = 0; r < 4; ++r) {
        int rr = row0 + quad * 4 + r;
        di[r] = (rr < N_NODES) ? rsqrtf((float)(cnt[rr] + 1)) : 0.f;
    }
#pragma unroll
    for (int nt = 0; nt < 8; ++nt) {
        f32x4 acc = {0.f, 0.f, 0.f, 0.f};
#pragma unroll
        for (int kc = 0; kc < 4; ++kc) {
            bf16x8 b = *(const bf16x8*)(Ws + ((size_t)(nt * 4 + kc) * 64 + lane) * 8);
            acc = __builtin_amdgcn_mfma_f32_16x16x32_bf16(a[kc], b, acc, 0, 0, 0);
        }
        int col = nt * 16 + m;
#pragma unroll
        for (int r = 0; r < 4; ++r) {
            int rr = row0 + quad * 4 + r;
            if (rr < N_NODES) Y[(size_t)rr * DIM + col] = f2bf(acc[r] * di[r]);
        }
    }
}

// ================= fused agg1 + gemm2 (16 nodes/block; 50000 = 3125*16) =================
__global__ __launch_bounds__(256) void k_agg_gemm(const u16* __restrict__ H,
                                                  const int* __restrict__ bucket,
                                                  const int* __restrict__ cnt,
                                                  const float* __restrict__ bias,
                                                  const u16* __restrict__ Ws,
                                                  u16* __restrict__ Y) {
    __shared__ u16 As[16][LDSS];
    int tid    = threadIdx.x;
    int nloc   = tid >> 4;
    int lane16 = tid & 15;
    int node   = blockIdx.x * 16 + nloc;

    // ---- phase A: quarter-wave aggregate ----
    int deg = cnt[node];
    int e0 = node * CAP, e1 = e0 + deg;
    const uint4* H4 = (const uint4*)H;
    uint4 sv = H4[(size_t)node * 16 + lane16];
    float a0[8], a1[8] = {}, a2[8] = {}, a3[8] = {};
    upk(sv.x, a0[0], a0[1]); upk(sv.y, a0[2], a0[3]);
    upk(sv.z, a0[4], a0[5]); upk(sv.w, a0[6], a0[7]);
    for (int e = e0; e < e1; e += 8) {
        int   idx[8];
        float w[8];
        uint4 v[8];
#pragma unroll
        for (int u = 0; u < 8; ++u) {
            int eu = e + u;
            int ec = min(eu, e1 - 1);
            idx[u] = bucket[ec];
            w[u]   = (eu < e1) ? 1.f : 0.f;
        }
#pragma unroll
        for (int u = 0; u < 8; ++u) v[u] = H4[(size_t)idx[u] * 16 + lane16];
#pragma unroll
        for (int u = 0; u < 8; ++u) {
            float* a = (u & 3) == 0 ? a0 : (u & 3) == 1 ? a1 : (u & 3) == 2 ? a2 : a3;
            float lo, hi;
            upk(v[u].x, lo, hi); a[0] = fmaf(w[u], lo, a[0]); a[1] = fmaf(w[u], hi, a[1]);
            upk(v[u].y, lo, hi); a[2] = fmaf(w[u], lo, a[2]); a[3] = fmaf(w[u], hi, a[3]);
            upk(v[u].z, lo, hi); a[4] = fmaf(w[u], lo, a[4]); a[5] = fmaf(w[u], hi, a[5]);
            upk(v[u].w, lo, hi); a[6] = fmaf(w[u], lo, a[6]); a[7] = fmaf(w[u], hi, a[7]);
        }
    }
    {
        float di = rsqrtf((float)(deg + 1));
        const float4* b4 = (const float4*)bias;
        float4 blo = b4[lane16 * 2], bhi = b4[lane16 * 2 + 1];
        float r0 = fmaxf(di * (a0[0] + a1[0] + a2[0] + a3[0]) + blo.x, 0.f);
        float r1 = fmaxf(di * (a0[1] + a1[1] + a2[1] + a3[1]) + blo.y, 0.f);
        float r2 = fmaxf(di * (a0[2] + a1[2] + a2[2] + a3[2]) + blo.z, 0.f);
        float r3 = fmaxf(di * (a0[3] + a1[3] + a2[3] + a3[3]) + blo.w, 0.f);
        float r4 = fmaxf(di * (a0[4] + a1[4] + a2[4] + a3[4]) + bhi.x, 0.f);
        float r5 = fmaxf(di * (a0[5] + a1[5] + a2[5] + a3[5]) + bhi.y, 0.f);
        float r6 = fmaxf(di * (a0[6] + a1[6] + a2[6] + a3[6]) + bhi.z, 0.f);
        float r7 = fmaxf(di * (a0[7] + a1[7] + a2[7] + a3[7]) + bhi.w, 0.f);
        short2 s0 = cvt2(r0, r1), s1 = cvt2(r2, r3), s2 = cvt2(r4, r5), s3 = cvt2(r6, r7);
        uint4 o;
        o.x = *(unsigned*)&s0; o.y = *(unsigned*)&s1;
        o.z = *(unsigned*)&s2; o.w = *(unsigned*)&s3;
        *(uint4*)(&As[nloc][lane16 * 8]) = o;
    }
    __syncthreads();

    // ---- phase B: 16x128 @ 128x128 MFMA; wave wv owns cols wv*32..wv*32+31 ----
    int wv   = tid >> 6;
    int lane = tid & 63;
    int m    = lane & 15;
    int quad = lane >> 4;
    bf16x8 a[4];
#pragma unroll
    for (int kc = 0; kc < 4; ++kc)
        a[kc] = *(const bf16x8*)(&As[m][kc * 32 + quad * 8]);
    float di[4];
#pragma unroll
    for (int r = 0; r < 4; ++r)
        di[r] = rsqrtf((float)(cnt[blockIdx.x * 16 + quad * 4 + r] + 1));
#pragma unroll
    for (int i = 0; i < 2; ++i) {
        int nt = wv * 2 + i;
        f32x4 acc = {0.f, 0.f, 0.f, 0.f};
#pragma unroll
        for (int kc = 0; kc < 4; ++kc) {
            bf16x8 b = *(const bf16x8*)(Ws + ((size_t)(nt * 4 + kc) * 64 + lane) * 8);
            acc = __builtin_amdgcn_mfma_f32_16x16x32_bf16(a[kc], b, acc, 0, 0, 0);
        }
        int col = nt * 16 + m;
#pragma unroll
        for (int r = 0; r < 4; ++r) {
            int rr = blockIdx.x * 16 + quad * 4 + r;
            Y[(size_t)rr * DIM + col] = f2bf(acc[r] * di[r]);
        }
    }
}

// ================= agg layer 2 (quarter-wave) =================
__global__ __launch_bounds__(256) void k_agg(const u16* __restrict__ H,
                                             const int* __restrict__ bucket,
                                             const int* __restrict__ cnt,
                                             const float* __restrict__ bias,
                                             u16* __restrict__ Out) {
    int node = blockIdx.x * 16 + (threadIdx.x >> 4);
    int lane = threadIdx.x & 15;
    if (node >= N_NODES) return;
    int deg = cnt[node];
    int e0 = node * CAP, e1 = e0 + deg;
    const uint4* H4 = (const uint4*)H;
    uint4 sv = H4[(size_t)node * 16 + lane];
    float a0[8], a1[8] = {}, a2[8] = {}, a3[8] = {};
    upk(sv.x, a0[0], a0[1]); upk(sv.y, a0[2], a0[3]);
    upk(sv.z, a0[4], a0[5]); upk(sv.w, a0[6], a0[7]);
    for (int e = e0; e < e1; e += 8) {
        int   idx[8];
        float w[8];
        uint4 v[8];
#pragma unroll
        for (int u = 0; u < 8; ++u) {
            int eu = e + u;
            int ec = min(eu, e1 - 1);
            idx[u] = bucket[ec];
            w[u]   = (eu < e1) ? 1.f : 0.f;
        }
#pragma unroll
        for (int u = 0; u < 8; ++u) v[u] = H4[(size_t)idx[u] * 16 + lane];
#pragma unroll
        for (int u = 0; u < 8; ++u) {
            float* a = (u & 3) == 0 ? a0 : (u & 3) == 1 ? a1 : (u & 3) == 2 ? a2 : a3;
            float lo, hi;
            upk(v[u].x, lo, hi); a[0] = fmaf(w[u], lo, a[0]); a[1] = fmaf(w[u], hi, a[1]);
            upk(v[u].y, lo, hi); a[2] = fmaf(w[u], lo, a[2]); a[3] = fmaf(w[u], hi, a[3]);
            upk(v[u].z, lo, hi); a[4] = fmaf(w[u], lo, a[4]); a[5] = fmaf(w[u], hi, a[5]);
            upk(v[u].w, lo, hi); a[6] = fmaf(w[u], lo, a[6]); a[7] = fmaf(w[u], hi, a[7]);
        }
    }
    float di = rsqrtf((float)(deg + 1));
    const float4* b4 = (const float4*)bias;
    float4 blo = b4[lane * 2], bhi = b4[lane * 2 + 1];
    float r0 = fmaxf(di * (a0[0] + a1[0] + a2[0] + a3[0]) + blo.x, 0.f);
    float r1 = fmaxf(di * (a0[1] + a1[1] + a2[1] + a3[1]) + blo.y, 0.f);
    float r2 = fmaxf(di * (a0[2] + a1[2] + a2[2] + a3[2]) + blo.z, 0.f);
    float r3 = fmaxf(di * (a0[3] + a1[3] + a2[3] + a3[3]) + blo.w, 0.f);
    float r4 = fmaxf(di * (a0[4] + a1[4] + a2[4] + a3[4]) + bhi.x, 0.f);
    float r5 = fmaxf(di * (a0[5] + a1[5] + a2[5] + a3[5]) + bhi.y, 0.f);
    float r6 = fmaxf(di * (a0[6] + a1[6] + a2[6] + a3[6]) + bhi.z, 0.f);
    float r7 = fmaxf(di * (a0[7] + a1[7] + a2[7] + a3[7]) + bhi.w, 0.f);
    short2 s0 = cvt2(r0, r1), s1 = cvt2(r2, r3), s2 = cvt2(r4, r5), s3 = cvt2(r6, r7);
    uint4 o;
    o.x = *(unsigned*)&s0; o.y = *(unsigned*)&s1;
    o.z = *(unsigned*)&s2; o.w = *(unsigned*)&s3;
    ((uint4*)Out)[(size_t)node * 16 + lane] = o;
}

// ---- global add pool over sorted batch: register run-length + atomic flush ----
// 1563 blocks (R10 lesson: 64-block fused pool_head was 96us latency-bound;
// R2 lesson: never per-lane atomics into 8K hot addresses).
__global__ __launch_bounds__(128) void k_pool(const u16* __restrict__ H,
                                              const int* __restrict__ batch,
                                              float* __restrict__ pooled) {
    int dim   = threadIdx.x;
    int start = blockIdx.x * POOL_CHUNK;
    if (start >= N_NODES) return;
    int end = min(start + POOL_CHUNK, N_NODES);
    float acc = 0.f;
    int cb = batch[start];
    for (int i = start; i < end; ++i) {
        int b = batch[i];
        if (b != cb) {
            atomicAdd(&pooled[cb * DIM + dim], acc);
            acc = 0.f; cb = b;
        }
        acc += bf2f(H[(size_t)i * DIM + dim]);
    }
    atomicAdd(&pooled[cb * DIM + dim], acc);
}

// ---- head: logits = pooled @ Wh + bh ; log_softmax per graph ----
__global__ __launch_bounds__(64) void k_head(const float* __restrict__ pooled,
                                             const float* __restrict__ Wh,
                                             const float* __restrict__ bh,
                                             float* __restrict__ out) {
    int g = blockIdx.x;
    int lane = threadIdx.x;
    int c = lane & 31;
    const float* p = pooled + g * DIM;
    float lg = bh[c];
#pragma unroll 8
    for (int k = 0; k < DIM; ++k) lg = fmaf(p[k], Wh[k * DOUT + c], lg);
    float m = lg;
    for (int off = 16; off >= 1; off >>= 1) m = fmaxf(m, __shfl_xor(m, off, 32));
    float ex = expf(lg - m);
    float s = ex;
    for (int off = 16; off >= 1; off >>= 1) s += __shfl_xor(s, off, 32);
    if (lane < 32) out[g * DOUT + c] = lg - m - logf(s);
}

extern "C" void kernel_launch(void* const* d_in, const int* in_sizes, int n_in,
                              void* d_out, int out_size, void* d_ws, size_t ws_size,
                              hipStream_t stream) {
    const float* x     = (const float*)d_in[0];
    const int*   ei    = (const int*)d_in[1];
    const int*   batch = (const int*)d_in[2];
    const float* W1    = (const float*)d_in[3];
    const float* b1    = (const float*)d_in[4];
    const float* W2    = (const float*)d_in[5];
    const float* b2    = (const float*)d_in[6];
    const float* Wh    = (const float*)d_in[7];
    const float* bh    = (const float*)d_in[8];
    float* out = (float*)d_out;
    const int* src = ei;
    const int* dst = ei + N_EDGES;

    char* ws = (char*)d_ws;
    size_t off = 0;
    auto alloc = [&](size_t bytes) {
        void* p = ws + off;
        off += (bytes + 255) & ~(size_t)255;
        return p;
    };
    u16*   bufA   = (u16*) alloc((size_t)N_NODES * DIM * 2);   // 12.8 MB bf16
    u16*   bufB   = (u16*) alloc((size_t)N_NODES * DIM * 2);   // 12.8 MB bf16
    int*   cnt    = (int*) alloc((size_t)N_NODES * 4);
    int*   bucket = (int*) alloc((size_t)N_NODES * CAP * 4);   // 12.8 MB
    u16*   W1s    = (u16*) alloc((size_t)DIM * DIM * 2);
    u16*   W2s    = (u16*) alloc((size_t)DIM * DIM * 2);
    float* pooled = (float*)alloc((size_t)NGRAPH * DIM * 4);
    (void)ws_size; (void)in_sizes; (void)n_in; (void)out_size;

    hipMemsetAsync(cnt, 0, (size_t)N_NODES * 4, stream);

    k_fill_cvt<<<CNT_BLOCKS + 128 + 32, 256, 0, stream>>>(src, dst, cnt, bucket,
                                                          W1, W2, W1s, W2s, pooled);

    k_gemm1   <<<(N_NODES + 63) / 64, 256, 0, stream>>>(x, W1s, cnt, bufA);
    k_agg_gemm<<<N_NODES / 16, 256, 0, stream>>>(bufA, bucket, cnt, b1, W2s, bufB);
    k_agg     <<<N_NODES / 16, 256, 0, stream>>>(bufB, bucket, cnt, b2, bufA);

    k_pool<<<(N_NODES + POOL_CHUNK - 1) / POOL_CHUNK, 128, 0, stream>>>(bufA, batch, pooled);
    k_head<<<NGRAPH, 64, 0, stream>>>(pooled, Wh, bh, out);
}